// Round 22
// baseline (746.913 us; speedup 1.0000x reference)
//
#include <hip/hip_runtime.h>
#include <hip/hip_fp16.h>

// Bidirectional char-LSTM + masked max-pool via MFMA — XE precompute (GEMM
// style) + CH=1 recurrent with 512 blocks for 2-blocks/CU co-residency.
// R21 lessons: (1) precompute must tile Wih in LDS (old one re-read 102KB
// x20000 blocks = ~300us); (2) grid 256 = 1 block/CU BY CONSTRUCTION --
// co-residency needs >256 blocks; K=128 shrink gives VGPR ~68 (+16 acc) so
// 4 waves/SIMD = 2 independent 8-wave blocks now fit the register file.
// Kernel 1: xe[dir][10000][512] f16 = emb.Wih^T + bias, slot-ordered so the
//   recurrent acc-init is 4x 8B broadcast gathers. 160 blocks x 512 thr,
//   Wih in LDS (slot-ordered, conflict-free), emb via uniform scalar loads.
// Kernel 2: 512 blocks = 2 dirs x 256 chains, 512 thr. K=128 (Whh only,
//   64 VGPR), 16 MFMA/wave/step, compact Hc[2][128] broadcast b128 reads,
//   role-split activation (DPP xor8), pair-packed writeback (xor1),
//   one barrier/step. Two blocks/CU hide each other's latency chains.
// Fallback if ws < 20.5MB: R17 kernel (381 us).

#define TT 512
#define VC 125
#define XE_U16 (2 * 10000 * 512)

typedef _Float16 f16;
typedef _Float16 f16x8 __attribute__((ext_vector_type(8)));
typedef float f32x4 __attribute__((ext_vector_type(4)));
typedef unsigned int u32;
typedef unsigned short u16;

static __device__ __forceinline__ u32 packh2(float lo, float hi) {
    union { struct { f16 x, y; } h; u32 u; } cv;
    cv.h.x = (f16)lo; cv.h.y = (f16)hi;
    return cv.u;
}
static __device__ __forceinline__ u16 f16bits(float v) {
    union { f16 h; u16 u; } cv; cv.h = (f16)v; return cv.u;
}
static __device__ __forceinline__ float fexp(float x) {
    return __builtin_amdgcn_exp2f(x * 1.44269504088896341f);
}
static __device__ __forceinline__ float frcp(float x) {
    return __builtin_amdgcn_rcpf(x);
}
static __device__ __forceinline__ float sigf(float x) {
    return frcp(1.f + fexp(-x));
}
static __device__ __forceinline__ float xor8(float x) {
    union { float f; int i; } c; c.f = x;
    c.i = __builtin_amdgcn_mov_dpp(c.i, 0x128, 0xF, 0xF, false);
    return c.f;
}
static __device__ __forceinline__ float xor1(float x) {
    union { float f; int i; } c; c.f = x;
    c.i = __builtin_amdgcn_mov_dpp(c.i, 0xB1, 0xF, 0xF, false);
    return c.f;
}
static __device__ __forceinline__ float xor2(float x) {
    union { float f; int i; } c; c.f = x;
    c.i = __builtin_amdgcn_mov_dpp(c.i, 0x4E, 0xF, 0xF, false);
    return c.f;
}
static __device__ __forceinline__ float sel4(f32x4 v, int q) {
    return (q & 2) ? ((q & 1) ? v[3] : v[2]) : ((q & 1) ? v[1] : v[0]);
}
static __device__ __forceinline__ f32x4 cvt4(uint2 u) {
    union { uint2 u2; f16 h[4]; } cv; cv.u2 = u;
    f32x4 r;
    r[0] = (float)cv.h[0]; r[1] = (float)cv.h[1];
    r[2] = (float)cv.h[2]; r[3] = (float)cv.h[3];
    return r;
}

// ---------------- Kernel 1: xe precompute, Wih tiled in LDS --------------
// grid 160 = dir*80 + chunk (125 vocab rows each). Thread s owns xe slot s:
// s = U*4 + q, U = wv*16 + gt*4 + c4, gate n = (wv+gt*8)*16 + c4*4 + q.
__global__ __launch_bounds__(512)
void xe_pre2_kernel(const float* __restrict__ emb,
                    const float* __restrict__ Wih_f,
                    const float* __restrict__ bih_f, const float* __restrict__ bhh_f,
                    const float* __restrict__ Wih_b,
                    const float* __restrict__ bih_b, const float* __restrict__ bhh_b,
                    u16* __restrict__ xe)
{
    const int bid   = blockIdx.x;
    const int ddir  = bid / 80;
    const int chunk = bid % 80;
    const int row0  = chunk * VC;
    const float* Wih = ddir ? Wih_b : Wih_f;
    const float* bih = ddir ? bih_b : bih_f;
    const float* bhh = ddir ? bhh_b : bhh_f;

    __shared__ u16 wih_s[50 * 512];   // slot-ordered: [k][s], 51.2 KB

    const int s  = threadIdx.x;
    const int U  = s >> 2, q = s & 3;
    const int wv = U >> 4, gt = (U >> 2) & 3, c4 = U & 3;
    const int n  = (wv + gt * 8) * 16 + c4 * 4 + q;   // gate row for slot s

#pragma unroll 5
    for (int k = 0; k < 50; ++k)
        wih_s[k * 512 + s] = f16bits(Wih[n * 50 + k]);
    const float bias = bih[n] + bhh[n];
    __syncthreads();

    u16* dst = xe + ((size_t)(ddir * 10000 + row0)) * 512 + s;
    for (int v = 0; v < VC; ++v) {
        const float* er = emb + (row0 + v) * 50;   // uniform -> scalar loads
        float acc = bias;
#pragma unroll
        for (int k = 0; k < 25; ++k) {
            const float2 e2 = *(const float2*)(er + 2 * k);
            union { u16 u; f16 h; } a, b;
            a.u = wih_s[(2 * k) * 512 + s];
            b.u = wih_s[(2 * k + 1) * 512 + s];
            acc += e2.x * (float)a.h + e2.y * (float)b.h;
        }
        dst[(size_t)v * 512] = f16bits(acc);
    }
}

// ---------------- Kernel 2: recurrent loop, CH=1, 512 blocks -------------
__global__ __launch_bounds__(512)
void bilstm_xe1_kernel(const int* __restrict__ idx,
                       const float* __restrict__ masks,
                       const u16* __restrict__ xe,
                       const float* __restrict__ Whh_f,
                       const float* __restrict__ Whh_b,
                       float* __restrict__ out)
{
    // Hc[buf][k]: k 0..127 = h (x contribution lives in the acc init)
    __shared__ __align__(16) u16 Hc[2][128];   // 512 B
    __shared__ u16 idx16[TT];                  // 1 KB
    __shared__ u16 mbits[TT];                  // 1 KB

    const int tid  = threadIdx.x;
    const int lane = tid & 63;
    const int wv   = tid >> 6;        // wave 0..7
    const int l15  = lane & 15;
    const int c4   = lane >> 4;       // 0..3 (acc row group / B k-group)
    const int d    = blockIdx.x & 1;  // 0 fwd, 1 bwd
    const int b0   = blockIdx.x >> 1; // chain 0..255
    const int rev  = d;

    const int q   = l15 & 3;          // acc row within c4 group (the dim)
    const bool rB = (l15 >> 3) != 0;  // role: A = state-owner, B = helper

    const float* Whh = d ? Whh_b : Whh_f;

    // ---- init
    if (tid < TT) {
        idx16[tid] = (u16)idx[b0 * TT + tid];
        mbits[tid] = (masks[b0 * TT + tid] != 0.f) ? (u16)1 : (u16)0;
    }
    if (tid < 128) {                  // 2 x 128 u16 = 128 u32
        ((u32*)Hc)[tid] = 0u;
    }

    // ---- Whh fragments (A-operand): w[kt][gt], kt 0..3 covers k 0..127.
    // Lane provides A[row = gate][k]: gate n = (wv + gt*8)*16 + l15,
    // k = kt*32 + c4*8 + j.
    f16x8 w[4][4];
#pragma unroll
    for (int gt = 0; gt < 4; ++gt) {
        const int n = (wv + gt * 8) * 16 + l15;
#pragma unroll
        for (int kt = 0; kt < 4; ++kt) {
            const int kh = kt * 32 + c4 * 8;
            const float4 e0 = *(const float4*)(Whh + n * 128 + kh);
            const float4 e1 = *(const float4*)(Whh + n * 128 + kh + 4);
            w[kt][gt][0] = (f16)e0.x; w[kt][gt][1] = (f16)e0.y;
            w[kt][gt][2] = (f16)e0.z; w[kt][gt][3] = (f16)e0.w;
            w[kt][gt][4] = (f16)e1.x; w[kt][gt][5] = (f16)e1.y;
            w[kt][gt][6] = (f16)e1.z; w[kt][gt][7] = (f16)e1.w;
        }
    }

    __syncthreads();   // idx16/mbits/Hc-zero visible

    // ---- xe gather bases: unit U = wv*16 + gt*4 + c4; lane-independent ->
    // all 16 lanes of a group load the same 8B (broadcast, coalesced).
    const int ubase  = (wv * 16 + c4) * 4;     // u16 offset of gt=0 unit
    const size_t xdb = (size_t)d * 10000 * 512;

    // prefetch xw for step 0
    uint2 xw0, xw1, xw2, xw3;
    {
        const int t0  = rev ? (TT - 1) : 0;
        const u16* rb = xe + xdb + (size_t)idx16[t0] * 512 + ubase;
        xw0 = *(const uint2*)(rb);
        xw1 = *(const uint2*)(rb + 16);
        xw2 = *(const uint2*)(rb + 32);
        xw3 = *(const uint2*)(rb + 48);
    }

    float cst = 0.f, rm = -3e38f;
    const int hd = wv * 16 + c4 * 4 + q;   // this lane's dim
    const bool wbthr = (l15 == 0) | (l15 == 2);

    for (int s = 0; s < TT; ++s) {
        const int cur = s & 1;
        const int t   = rev ? (TT - 1 - s) : s;

        // acc init = xg(t): bias + x.Wih already folded in
        f32x4 ai = cvt4(xw0), af = cvt4(xw1), ag = cvt4(xw2), ao = cvt4(xw3);

        // prefetch next step's xe units (hidden under MFMA)
        const bool pf = (s + 1 < TT);
        if (pf) {
            const int t1  = rev ? (TT - 2 - s) : (s + 1);
            const u16* rb = xe + xdb + (size_t)idx16[t1] * 512 + ubase;
            xw0 = *(const uint2*)(rb);
            xw1 = *(const uint2*)(rb + 16);
            xw2 = *(const uint2*)(rb + 32);
            xw3 = *(const uint2*)(rb + 48);
        }

        // ---- MFMA: 4 gate tiles x 4 K-steps; B-frag = broadcast b128 read
        const unsigned char* hb = (const unsigned char*)&Hc[cur][0];
#pragma unroll
        for (int kt = 0; kt < 4; ++kt) {
            const f16x8 bf = *(const f16x8*)(hb + kt * 64 + c4 * 16);
            ai = __builtin_amdgcn_mfma_f32_16x16x32_f16(w[kt][0], bf, ai, 0, 0, 0);
            af = __builtin_amdgcn_mfma_f32_16x16x32_f16(w[kt][1], bf, af, 0, 0, 0);
            ag = __builtin_amdgcn_mfma_f32_16x16x32_f16(w[kt][2], bf, ag, 0, 0, 0);
            ao = __builtin_amdgcn_mfma_f32_16x16x32_f16(w[kt][3], bf, ao, 0, 0, 0);
        }

        // ---- q-row select (cols 16x duplicated -> all lanes valid)
        const float iv = sel4(ai, q);
        const float fv = sel4(af, q);
        const float gv = sel4(ag, q);
        const float ov = sel4(ao, q);

        // ---- role-split activation, DPP transport (proven R13-R17)
        const float u_in = rB ? (gv + gv) : fv;
        const float v_in = rB ? ov : iv;
        const float su = sigf(u_in);
        const float sv = sigf(v_in);
        const float tg_send = 2.f * su - 1.f;     // B: tanh(g); A: junk
        const float tgx = xor8(tg_send);          // A receives tanh(g)
        const float svx = xor8(sv);               // A receives sig(o)
        const float cc = su * cst + sv * tgx;     // A: valid c; B: junk
        cst = cc;
        const float ccx = xor8(cc);               // B receives A's cc
        const float cc_use = rB ? ccx : cc;
        const float th = 2.f * sigf(cc_use + cc_use) - 1.f;   // tanh(c)
        const float so_use = rB ? sv : svx;       // sig(o) in both roles
        const float hh = so_use * th;             // VALID in all lanes

        const float pen = mbits[t] ? 0.f : 1e8f;
        rm = fmaxf(rm, hh - pen);

        // ---- writeback: single copy, dim-pair packed via DPP xor1
        unsigned char* nb = (unsigned char*)&Hc[cur ^ 1][0];
        const float hx = xor1(hh);                // h of dim hd^1 (q odd)
        if (wbthr) {
            *(u32*)(nb + hd * 2) = packh2(hh, hx);
        }
        __syncthreads();
    }

    if (l15 < 4) {
        out[b0 * 256 + d * 128 + hd] = rm;
    }
}

// ---------------- Fallback: R17 kernel (381 us) --------------------------
__global__ __attribute__((amdgpu_flat_work_group_size(512, 512),
                          amdgpu_waves_per_eu(2, 2)))
void bilstm_compact_kernel(const int* __restrict__ idx,
                           const float* __restrict__ masks,
                           const float* __restrict__ emb,
                           const float* __restrict__ Wih_f, const float* __restrict__ Whh_f,
                           const float* __restrict__ bih_f, const float* __restrict__ bhh_f,
                           const float* __restrict__ Wih_b, const float* __restrict__ Whh_b,
                           const float* __restrict__ bih_b, const float* __restrict__ bhh_b,
                           float* __restrict__ out)
{
    __shared__ __align__(16) u16 Hc[2][2][192];
    __shared__ u16 idx16[2 * TT];
    __shared__ u32 mbits[TT];

    const int tid  = threadIdx.x;
    const int lane = tid & 63;
    const int wv   = tid >> 6;
    const int l15  = lane & 15;
    const int c4   = lane >> 4;
    const int d    = blockIdx.x & 1;
    const int g    = blockIdx.x >> 1;
    const int b0   = g * 2;
    const int rev  = d;
    const int chain = l15 & 1;
    const int q     = (l15 >> 1) & 3;
    const int role  = l15 >> 3;

    const float* Wih = d ? Wih_b : Wih_f;
    const float* Whh = d ? Whh_b : Whh_f;
    const float* bih = d ? bih_b : bih_f;
    const float* bhh = d ? bhh_b : bhh_f;

    for (int i = tid; i < 2 * TT; i += 512) {
        const int m = i >> 9, t = i & 511;
        idx16[i] = (u16)idx[(b0 + m) * TT + t];
    }
    if (tid < TT) {
        u32 mb = 0;
        for (int m = 0; m < 2; ++m)
            mb |= (masks[(b0 + m) * TT + tid] != 0.f ? 1u : 0u) << m;
        mbits[tid] = mb;
    }
    if (tid < 2 * 2 * 192 / 2) ((u32*)Hc)[tid] = 0u;

    f16x8 w[6][4];
    f32x4 bias4[4];
#pragma unroll
    for (int gt = 0; gt < 4; ++gt) {
        const int n = (wv + gt * 8) * 16 + l15;
        {
            const int nb_ = (wv + gt * 8) * 16 + c4 * 4;
            const float4 bi = *(const float4*)(bih + nb_);
            const float4 bh = *(const float4*)(bhh + nb_);
            bias4[gt][0] = bi.x + bh.x; bias4[gt][1] = bi.y + bh.y;
            bias4[gt][2] = bi.z + bh.z; bias4[gt][3] = bi.w + bh.w;
        }
#pragma unroll
        for (int jj = 0; jj < 4; ++jj) {
            const float2 e = *(const float2*)(Wih + n * 50 + c4 * 8 + jj * 2);
            w[0][gt][2 * jj]     = (f16)e.x;
            w[0][gt][2 * jj + 1] = (f16)e.y;
        }
#pragma unroll
        for (int j = 0; j < 8; ++j) {
            const int k = 32 + c4 * 8 + j;
            float v = 0.f;
            if (k < 50) v = Wih[n * 50 + k];
            w[1][gt][j] = (f16)v;
        }
#pragma unroll
        for (int kt = 2; kt < 6; ++kt) {
            const int kh = (kt - 2) * 32 + c4 * 8;
            const float4 e0 = *(const float4*)(Whh + n * 128 + kh);
            const float4 e1 = *(const float4*)(Whh + n * 128 + kh + 4);
            w[kt][gt][0] = (f16)e0.x; w[kt][gt][1] = (f16)e0.y;
            w[kt][gt][2] = (f16)e0.z; w[kt][gt][3] = (f16)e0.w;
            w[kt][gt][4] = (f16)e1.x; w[kt][gt][5] = (f16)e1.y;
            w[kt][gt][6] = (f16)e1.z; w[kt][gt][7] = (f16)e1.w;
        }
    }
    __syncthreads();

    const int  tid7 = tid - 448;
    const bool xthr = (tid7 >= 0) && (tid7 < 50);
    const int  xch  = xthr ? (tid7 / 25) : 0;
    const int  xps  = xthr ? (tid7 % 25) : 0;
    if (xthr) {
        const int t0  = rev ? (TT - 1) : 0;
        const int row = idx16[xch * TT + t0];
        const float2 e = *(const float2*)(emb + row * 50 + xps * 2);
        *(u32*)((unsigned char*)&Hc[0][0][0] + xch * 384 + xps * 4) =
            packh2(e.x, e.y);
    }
    __syncthreads();

    float cst = 0.f, rm = -3e38f;
    const int hd = wv * 16 + c4 * 4 + q;
    const bool wbthr = (l15 == 0) | (l15 == 1) | (l15 == 4) | (l15 == 5);

    for (int s = 0; s < TT; ++s) {
        const int cur = s & 1;
        const int t   = rev ? (TT - 1 - s) : s;
        float2 e;
        const bool pf = xthr && (s + 1 < TT);
        if (pf) {
            const int t1  = rev ? (TT - 2 - s) : (s + 1);
            const int row = idx16[xch * TT + t1];
            e = *(const float2*)(emb + row * 50 + xps * 2);
        }
        const unsigned char* hb =
            (const unsigned char*)&Hc[cur][0][0] + chain * 384;
        f32x4 ai = bias4[0], af = bias4[1], ag = bias4[2], ao = bias4[3];
#pragma unroll
        for (int kt = 0; kt < 6; ++kt) {
            const f16x8 bf = *(const f16x8*)(hb + kt * 64 + c4 * 16);
            ai = __builtin_amdgcn_mfma_f32_16x16x32_f16(w[kt][0], bf, ai, 0, 0, 0);
            af = __builtin_amdgcn_mfma_f32_16x16x32_f16(w[kt][1], bf, af, 0, 0, 0);
            ag = __builtin_amdgcn_mfma_f32_16x16x32_f16(w[kt][2], bf, ag, 0, 0, 0);
            ao = __builtin_amdgcn_mfma_f32_16x16x32_f16(w[kt][3], bf, ao, 0, 0, 0);
        }
        const float iv = sel4(ai, q);
        const float fv = sel4(af, q);
        const float gv = sel4(ag, q);
        const float ov = sel4(ao, q);
        const bool rB = (role != 0);
        const float u_in = rB ? (gv + gv) : fv;
        const float v_in = rB ? ov : iv;
        const float su = sigf(u_in);
        const float sv = sigf(v_in);
        const float tg_send = 2.f * su - 1.f;
        const float tgx = xor8(tg_send);
        const float svx = xor8(sv);
        const float cc = su * cst + sv * tgx;
        cst = cc;
        const float ccx = xor8(cc);
        const float cc_use = rB ? ccx : cc;
        const float th = 2.f * sigf(cc_use + cc_use) - 1.f;
        const float so_use = rB ? sv : svx;
        const float hh = so_use * th;
        const float pen = ((mbits[t] >> chain) & 1u) ? 0.f : 1e8f;
        rm = fmaxf(rm, hh - pen);
        unsigned char* nb = (unsigned char*)&Hc[cur ^ 1][0][0];
        const float hx2 = xor2(hh);
        if (wbthr) {
            *(u32*)(nb + chain * 384 + 128 + hd * 2) = packh2(hh, hx2);
        }
        if (pf) {
            *(u32*)(nb + xch * 384 + xps * 4) = packh2(e.x, e.y);
        }
        __syncthreads();
    }
    if (l15 < 8) {
        out[(b0 + chain) * 256 + d * 128 + hd] = rm;
    }
}

extern "C" void kernel_launch(void* const* d_in, const int* in_sizes, int n_in,
                              void* d_out, int out_size, void* d_ws, size_t ws_size,
                              hipStream_t stream) {
    const int*   idx   = (const int*)d_in[0];
    const float* masks = (const float*)d_in[1];
    const float* emb   = (const float*)d_in[2];
    const float* Wih_f = (const float*)d_in[3];
    const float* Whh_f = (const float*)d_in[4];
    const float* bih_f = (const float*)d_in[5];
    const float* bhh_f = (const float*)d_in[6];
    const float* Wih_b = (const float*)d_in[7];
    const float* Whh_b = (const float*)d_in[8];
    const float* bih_b = (const float*)d_in[9];
    const float* bhh_b = (const float*)d_in[10];
    float* out = (float*)d_out;

    const size_t xe_bytes = (size_t)XE_U16 * sizeof(u16);   // 20.48 MB
    if (ws_size >= xe_bytes) {
        u16* xe = (u16*)d_ws;
        xe_pre2_kernel<<<dim3(160), dim3(512), 0, stream>>>(
            emb, Wih_f, bih_f, bhh_f, Wih_b, bih_b, bhh_b, xe);
        bilstm_xe1_kernel<<<dim3(512), dim3(512), 0, stream>>>(
            idx, masks, xe, Whh_f, Whh_b, out);
    } else {
        bilstm_compact_kernel<<<dim3(256), dim3(512), 0, stream>>>(
            idx, masks, emb,
            Wih_f, Whh_f, bih_f, bhh_f,
            Wih_b, Whh_b, bih_b, bhh_b,
            out);
    }
}

// Round 23
// 408.832 us; speedup vs baseline: 1.8269x; 1.8269x over previous
//
#include <hip/hip_runtime.h>
#include <hip/hip_fp16.h>

// Bidirectional char-LSTM + masked max-pool via MFMA — COMPACT H (R17 base)
// + SPLIT K-ACCUMULATORS.
// 256 blocks = 2 dirs x 128 chain-pairs (CH=2), 512 threads, 8 waves.
// R17 (381us, best): compact Hc broadcast reads, role-split activation,
// single-copy writeback, 1 barrier/step. Its MfmaUtil=42% implies ~750
// busy-cyc/step vs ~230 issue -> dependent-MFMA latency (~32cyc) stalls the
// distance-4 accumulation chains (~13cyc/MFMA). R23: split each gate's
// K-chain into TWO independent accumulators (kt 0-2 / 3-5, interleaved
// issue, dep distance 8 instr ~38cyc >= latency) -> pipelined; combine with
// one f32x4 add per gate after the loop. Everything else identical to R17.
// R21/R22 closed: xe-precompute gathers are latency-bound and co-residency
// requires reported VGPR<=64 (unreachable with 64-reg weight arrays).

#define TT 512
#define CH 2

typedef _Float16 f16;
typedef _Float16 f16x8 __attribute__((ext_vector_type(8)));
typedef float f32x4 __attribute__((ext_vector_type(4)));
typedef unsigned int u32;
typedef unsigned short u16;

static __device__ __forceinline__ u32 packh2(float lo, float hi) {
    union { struct { f16 x, y; } h; u32 u; } cv;
    cv.h.x = (f16)lo; cv.h.y = (f16)hi;
    return cv.u;
}
static __device__ __forceinline__ float fexp(float x) {
    return __builtin_amdgcn_exp2f(x * 1.44269504088896341f);
}
static __device__ __forceinline__ float frcp(float x) {
    return __builtin_amdgcn_rcpf(x);
}
static __device__ __forceinline__ float sigf(float x) {
    return frcp(1.f + fexp(-x));
}
static __device__ __forceinline__ float xor8(float x) {
    // lane <-> lane^8: DPP row_ror:8 (rotate within rows of 16 == xor 8)
    union { float f; int i; } c; c.f = x;
    c.i = __builtin_amdgcn_mov_dpp(c.i, 0x128, 0xF, 0xF, false);
    return c.f;
}
static __device__ __forceinline__ float xor2(float x) {
    // lane <-> lane^2: quad_perm(2,3,0,1) = 0x4E
    union { float f; int i; } c; c.f = x;
    c.i = __builtin_amdgcn_mov_dpp(c.i, 0x4E, 0xF, 0xF, false);
    return c.f;
}
static __device__ __forceinline__ float sel4(f32x4 v, int q) {
    // q in 0..3, compile-time indices in each arm (no dynamic indexing)
    return (q & 2) ? ((q & 1) ? v[3] : v[2]) : ((q & 1) ? v[1] : v[0]);
}

__global__ __attribute__((amdgpu_flat_work_group_size(512, 512),
                          amdgpu_waves_per_eu(2, 2)))
void bilstm_compact2_kernel(const int* __restrict__ idx,
                            const float* __restrict__ masks,
                            const float* __restrict__ emb,
                            const float* __restrict__ Wih_f, const float* __restrict__ Whh_f,
                            const float* __restrict__ bih_f, const float* __restrict__ bhh_f,
                            const float* __restrict__ Wih_b, const float* __restrict__ Whh_b,
                            const float* __restrict__ bih_b, const float* __restrict__ bhh_b,
                            float* __restrict__ out)
{
    // Hc[buf][chain][k]: k 0..49 = x, 50..63 = 0 pad, 64..191 = h[k-64]
    __shared__ __align__(16) u16 Hc[2][CH][192];   // 1.5 KB
    __shared__ u16 idx16[CH * TT];                 // 2 KB
    __shared__ u32 mbits[TT];                      // 2 KB

    const int tid  = threadIdx.x;
    const int lane = tid & 63;
    const int wv   = tid >> 6;        // wave 0..7
    const int l15  = lane & 15;       // acc col
    const int c4   = lane >> 4;       // 0..3 (acc row group / B k-group)
    const int d    = blockIdx.x & 1;  // 0 fwd, 1 bwd
    const int g    = blockIdx.x >> 1; // 0..127
    const int b0   = g * CH;
    const int rev  = d;

    const int chain = l15 & 1;
    const int q     = (l15 >> 1) & 3; // acc row within c4 group
    const int role  = l15 >> 3;       // 0 = A (state-owner), 1 = B (helper)

    const float* Wih = d ? Wih_b : Wih_f;
    const float* Whh = d ? Whh_b : Whh_f;
    const float* bih = d ? bih_b : bih_f;
    const float* bhh = d ? bhh_b : bhh_f;

    // ---- init: idx (u16), mask bits, zero Hc (pads stay 0 forever)
    for (int i = tid; i < CH * TT; i += 512) {
        const int m = i >> 9, t = i & 511;
        idx16[i] = (u16)idx[(b0 + m) * TT + t];
    }
    if (tid < TT) {
        u32 mb = 0;
        for (int m = 0; m < CH; ++m)
            mb |= (masks[(b0 + m) * TT + tid] != 0.f ? 1u : 0u) << m;
        mbits[tid] = mb;
    }
    if (tid < 2 * CH * 192 / 2) {          // 384 u32s
        ((u32*)Hc)[tid] = 0u;
    }

    // ---- W fragments (A-operand) in VGPRs: w[kt][gt], gt = i/f/g/o.
    // Lane provides A[row = gate][k]: gate n = (wv + gt*8)*16 + l15,
    // k = kt*32 + c4*8 + j, j = 0..7.  (identical to R9-R17, proven)
    f16x8 w[6][4];
    f32x4 bias4[4];
#pragma unroll
    for (int gt = 0; gt < 4; ++gt) {
        const int n = (wv + gt * 8) * 16 + l15;
        {   // bias for acc rows: gates (wv+gt*8)*16 + c4*4 + q', q'=0..3
            const int nb_ = (wv + gt * 8) * 16 + c4 * 4;
            const float4 bi = *(const float4*)(bih + nb_);
            const float4 bh = *(const float4*)(bhh + nb_);
            bias4[gt][0] = bi.x + bh.x; bias4[gt][1] = bi.y + bh.y;
            bias4[gt][2] = bi.z + bh.z; bias4[gt][3] = bi.w + bh.w;
        }
        // kt = 0: k = c4*8 + j (< 32 < 50) -> Wih (float2 loads: 8B aligned)
#pragma unroll
        for (int jj = 0; jj < 4; ++jj) {
            const float2 e = *(const float2*)(Wih + n * 50 + c4 * 8 + jj * 2);
            w[0][gt][2 * jj]     = (f16)e.x;
            w[0][gt][2 * jj + 1] = (f16)e.y;
        }
        // kt = 1: k = 32 + c4*8 + j, real iff k < 50
#pragma unroll
        for (int j = 0; j < 8; ++j) {
            const int k = 32 + c4 * 8 + j;
            float v = 0.f;
            if (k < 50) v = Wih[n * 50 + k];
            w[1][gt][j] = (f16)v;
        }
        // kt = 2..5: k >= 64 -> Whh[n][k-64] (16B aligned float4 x2)
#pragma unroll
        for (int kt = 2; kt < 6; ++kt) {
            const int kh = (kt - 2) * 32 + c4 * 8;
            const float4 e0 = *(const float4*)(Whh + n * 128 + kh);
            const float4 e1 = *(const float4*)(Whh + n * 128 + kh + 4);
            w[kt][gt][0] = (f16)e0.x; w[kt][gt][1] = (f16)e0.y;
            w[kt][gt][2] = (f16)e0.z; w[kt][gt][3] = (f16)e0.w;
            w[kt][gt][4] = (f16)e1.x; w[kt][gt][5] = (f16)e1.y;
            w[kt][gt][6] = (f16)e1.z; w[kt][gt][7] = (f16)e1.w;
        }
    }

    __syncthreads();   // idx16/mbits/Hc-zero visible before x store

    // ---- x staging lanes: wave 7, 50 lanes (2 chains x 25 half-pairs)
    const int  tid7 = tid - 448;
    const bool xthr = (tid7 >= 0) && (tid7 < 50);
    const int  xch  = xthr ? (tid7 / 25) : 0;
    const int  xps  = xthr ? (tid7 % 25) : 0;

    // ---- x for step 0
    if (xthr) {
        const int t0  = rev ? (TT - 1) : 0;
        const int row = idx16[xch * TT + t0];
        const float2 e = *(const float2*)(emb + row * 50 + xps * 2);
        *(u32*)((unsigned char*)&Hc[0][0][0] + xch * 384 + xps * 4) =
            packh2(e.x, e.y);
    }
    __syncthreads();

    float cst = 0.f, rm = -3e38f;

    const int hd = wv * 16 + c4 * 4 + q;   // this lane's dim
    // writeback: lanes l15 in {0,1,4,5} (role 0, even q) write the dim-pair
    const bool wbthr = (l15 == 0) | (l15 == 1) | (l15 == 4) | (l15 == 5);

    for (int s = 0; s < TT; ++s) {
        const int cur = s & 1;
        const int t   = rev ? (TT - 1 - s) : s;

        // prefetch next step's x pair (wave 7; hidden under MFMA)
        float2 e;
        const bool pf = xthr && (s + 1 < TT);
        if (pf) {
            const int t1  = rev ? (TT - 2 - s) : (s + 1);
            const int row = idx16[xch * TT + t1];
            e = *(const float2*)(emb + row * 50 + xps * 2);
        }

        // ---- MFMA: 4 gate tiles x 6 K-steps, SPLIT ACCUMULATORS:
        // kt 0-2 -> acc0 (bias-initialized), kt 3-5 -> acc1 (zero-init).
        // Interleaved issue -> 8 independent chains, dep distance 8 instr.
        const unsigned char* hb =
            (const unsigned char*)&Hc[cur][0][0] + chain * 384;
        const f16x8 bf0 = *(const f16x8*)(hb + 0 * 64 + c4 * 16);
        const f16x8 bf1 = *(const f16x8*)(hb + 1 * 64 + c4 * 16);
        const f16x8 bf2 = *(const f16x8*)(hb + 2 * 64 + c4 * 16);
        const f16x8 bf3 = *(const f16x8*)(hb + 3 * 64 + c4 * 16);
        const f16x8 bf4 = *(const f16x8*)(hb + 4 * 64 + c4 * 16);
        const f16x8 bf5 = *(const f16x8*)(hb + 5 * 64 + c4 * 16);

        const f32x4 z = {0.f, 0.f, 0.f, 0.f};
        f32x4 ai0 = bias4[0], af0 = bias4[1], ag0 = bias4[2], ao0 = bias4[3];
        f32x4 ai1 = z,        af1 = z,        ag1 = z,        ao1 = z;

        ai0 = __builtin_amdgcn_mfma_f32_16x16x32_f16(w[0][0], bf0, ai0, 0, 0, 0);
        af0 = __builtin_amdgcn_mfma_f32_16x16x32_f16(w[0][1], bf0, af0, 0, 0, 0);
        ag0 = __builtin_amdgcn_mfma_f32_16x16x32_f16(w[0][2], bf0, ag0, 0, 0, 0);
        ao0 = __builtin_amdgcn_mfma_f32_16x16x32_f16(w[0][3], bf0, ao0, 0, 0, 0);
        ai1 = __builtin_amdgcn_mfma_f32_16x16x32_f16(w[3][0], bf3, ai1, 0, 0, 0);
        af1 = __builtin_amdgcn_mfma_f32_16x16x32_f16(w[3][1], bf3, af1, 0, 0, 0);
        ag1 = __builtin_amdgcn_mfma_f32_16x16x32_f16(w[3][2], bf3, ag1, 0, 0, 0);
        ao1 = __builtin_amdgcn_mfma_f32_16x16x32_f16(w[3][3], bf3, ao1, 0, 0, 0);
        ai0 = __builtin_amdgcn_mfma_f32_16x16x32_f16(w[1][0], bf1, ai0, 0, 0, 0);
        af0 = __builtin_amdgcn_mfma_f32_16x16x32_f16(w[1][1], bf1, af0, 0, 0, 0);
        ag0 = __builtin_amdgcn_mfma_f32_16x16x32_f16(w[1][2], bf1, ag0, 0, 0, 0);
        ao0 = __builtin_amdgcn_mfma_f32_16x16x32_f16(w[1][3], bf1, ao0, 0, 0, 0);
        ai1 = __builtin_amdgcn_mfma_f32_16x16x32_f16(w[4][0], bf4, ai1, 0, 0, 0);
        af1 = __builtin_amdgcn_mfma_f32_16x16x32_f16(w[4][1], bf4, af1, 0, 0, 0);
        ag1 = __builtin_amdgcn_mfma_f32_16x16x32_f16(w[4][2], bf4, ag1, 0, 0, 0);
        ao1 = __builtin_amdgcn_mfma_f32_16x16x32_f16(w[4][3], bf4, ao1, 0, 0, 0);
        ai0 = __builtin_amdgcn_mfma_f32_16x16x32_f16(w[2][0], bf2, ai0, 0, 0, 0);
        af0 = __builtin_amdgcn_mfma_f32_16x16x32_f16(w[2][1], bf2, af0, 0, 0, 0);
        ag0 = __builtin_amdgcn_mfma_f32_16x16x32_f16(w[2][2], bf2, ag0, 0, 0, 0);
        ao0 = __builtin_amdgcn_mfma_f32_16x16x32_f16(w[2][3], bf2, ao0, 0, 0, 0);
        ai1 = __builtin_amdgcn_mfma_f32_16x16x32_f16(w[5][0], bf5, ai1, 0, 0, 0);
        af1 = __builtin_amdgcn_mfma_f32_16x16x32_f16(w[5][1], bf5, af1, 0, 0, 0);
        ag1 = __builtin_amdgcn_mfma_f32_16x16x32_f16(w[5][2], bf5, ag1, 0, 0, 0);
        ao1 = __builtin_amdgcn_mfma_f32_16x16x32_f16(w[5][3], bf5, ao1, 0, 0, 0);

        // ---- combine split accumulators, then q-row select
        const f32x4 aiv = ai0 + ai1;
        const f32x4 afv = af0 + af1;
        const f32x4 agv = ag0 + ag1;
        const f32x4 aov = ao0 + ao1;
        const float iv = sel4(aiv, q);
        const float fv = sel4(afv, q);
        const float gv = sel4(agv, q);
        const float ov = sel4(aov, q);

        // ---- SIMT role-split activation, DPP transport (R13-R17 proven):
        // role A: su=sig(f), sv=sig(i); role B: su=sig(2g), sv=sig(o)
        const bool rB = (role != 0);
        const float u_in = rB ? (gv + gv) : fv;
        const float v_in = rB ? ov : iv;
        const float su = sigf(u_in);
        const float sv = sigf(v_in);
        const float tg_send = 2.f * su - 1.f;     // B: tanh(g); A: junk
        const float tgx = xor8(tg_send);          // A receives tanh(g)
        const float svx = xor8(sv);               // A receives sig(o)
        const float cc = su * cst + sv * tgx;     // A: valid c; B: junk chain
        cst = cc;
        const float ccx = xor8(cc);               // B receives A's cc
        const float cc_use = rB ? ccx : cc;
        const float th = 2.f * sigf(cc_use + cc_use) - 1.f;   // tanh(c)
        const float so_use = rB ? sv : svx;       // sig(o) in both roles
        const float hh = so_use * th;             // VALID in all lanes

        const float pen = ((mbits[t] >> chain) & 1u) ? 0.f : 1e8f;
        rm = fmaxf(rm, hh - pen);

        // ---- writeback: single copy, dim-pair packed via DPP xor2
        unsigned char* nb = (unsigned char*)&Hc[cur ^ 1][0][0];
        const float hx2 = xor2(hh);               // neighbor dim's h (q^1)
        if (wbthr) {
            // this lane q even: pk = (h[hd], h[hd+1]); addr 4B-aligned
            *(u32*)(nb + chain * 384 + 128 + hd * 2) = packh2(hh, hx2);
        }
        if (pf) {
            *(u32*)(nb + xch * 384 + xps * 4) = packh2(e.x, e.y);
        }
        __syncthreads();
    }

    // ---- output: lanes l15 < 8 give unique (chain, q) -> one per dim
    if (l15 < 8) {
        out[(b0 + chain) * 256 + d * 128 + hd] = rm;
    }
}

extern "C" void kernel_launch(void* const* d_in, const int* in_sizes, int n_in,
                              void* d_out, int out_size, void* d_ws, size_t ws_size,
                              hipStream_t stream) {
    const int*   idx   = (const int*)d_in[0];
    const float* masks = (const float*)d_in[1];
    const float* emb   = (const float*)d_in[2];
    const float* Wih_f = (const float*)d_in[3];
    const float* Whh_f = (const float*)d_in[4];
    const float* bih_f = (const float*)d_in[5];
    const float* bhh_f = (const float*)d_in[6];
    const float* Wih_b = (const float*)d_in[7];
    const float* Whh_b = (const float*)d_in[8];
    const float* bih_b = (const float*)d_in[9];
    const float* bhh_b = (const float*)d_in[10];
    float* out = (float*)d_out;

    bilstm_compact2_kernel<<<dim3(256), dim3(512), 0, stream>>>(
        idx, masks, emb,
        Wih_f, Whh_f, bih_f, bhh_f,
        Wih_b, Whh_b, bih_b, bhh_b,
        out);
}

// Round 24
// 373.995 us; speedup vs baseline: 1.9971x; 1.0931x over previous
//
#include <hip/hip_runtime.h>
#include <hip/hip_fp16.h>

// Bidirectional char-LSTM + masked max-pool via MFMA — COMPACT H (R17 base)
// + X-LOOKAHEAD (serial MFMA chain 6 -> 4).
// 256 blocks = 2 dirs x 128 chain-pairs (CH=2), 512 threads, 8 waves.
// R17 (381us): per-step critical path = barrier -> ds_read -> 6-deep MFMA
// chain -> activation -> writeback -> barrier. The x-part (kt 0-1) depends
// only on the INPUT, known ahead: stage x TWO steps ahead (3-slot rotating
// Xb buffer) and compute next step's x-partial acc (8 MFMAs, off-path)
// during the current step; the gate acc then starts from the carried xacc
// and needs only 4 h-dependent MFMAs. R23 lesson: don't hand-interleave
// chains (scheduler already does); this changes the DEPENDENCE STRUCTURE
// instead. Everything else identical to R17: compact Hc broadcast b128
// reads, role-split activation (DPP xor8), pair-packed single-copy
// writeback (xor2), one barrier/step.

#define TT 512
#define CH 2

typedef _Float16 f16;
typedef _Float16 f16x8 __attribute__((ext_vector_type(8)));
typedef float f32x4 __attribute__((ext_vector_type(4)));
typedef unsigned int u32;
typedef unsigned short u16;

static __device__ __forceinline__ u32 packh2(float lo, float hi) {
    union { struct { f16 x, y; } h; u32 u; } cv;
    cv.h.x = (f16)lo; cv.h.y = (f16)hi;
    return cv.u;
}
static __device__ __forceinline__ float fexp(float x) {
    return __builtin_amdgcn_exp2f(x * 1.44269504088896341f);
}
static __device__ __forceinline__ float frcp(float x) {
    return __builtin_amdgcn_rcpf(x);
}
static __device__ __forceinline__ float sigf(float x) {
    return frcp(1.f + fexp(-x));
}
static __device__ __forceinline__ float xor8(float x) {
    // lane <-> lane^8: DPP row_ror:8 (rotate within rows of 16 == xor 8)
    union { float f; int i; } c; c.f = x;
    c.i = __builtin_amdgcn_mov_dpp(c.i, 0x128, 0xF, 0xF, false);
    return c.f;
}
static __device__ __forceinline__ float xor2(float x) {
    // lane <-> lane^2: quad_perm(2,3,0,1) = 0x4E
    union { float f; int i; } c; c.f = x;
    c.i = __builtin_amdgcn_mov_dpp(c.i, 0x4E, 0xF, 0xF, false);
    return c.f;
}
static __device__ __forceinline__ float sel4(f32x4 v, int q) {
    // q in 0..3, compile-time indices in each arm (no dynamic indexing)
    return (q & 2) ? ((q & 1) ? v[3] : v[2]) : ((q & 1) ? v[1] : v[0]);
}

__global__ __attribute__((amdgpu_flat_work_group_size(512, 512),
                          amdgpu_waves_per_eu(2, 2)))
void bilstm_xla_kernel(const int* __restrict__ idx,
                       const float* __restrict__ masks,
                       const float* __restrict__ emb,
                       const float* __restrict__ Wih_f, const float* __restrict__ Whh_f,
                       const float* __restrict__ bih_f, const float* __restrict__ bhh_f,
                       const float* __restrict__ Wih_b, const float* __restrict__ Whh_b,
                       const float* __restrict__ bih_b, const float* __restrict__ bhh_b,
                       float* __restrict__ out)
{
    // Hc[buf][chain][dim]: h only (1 KB). Xb[slot][chain][k]: x k 0..63
    // (50 real, pads 0), 3 rotating slots (768 B).
    __shared__ __align__(16) u16 Hc[2][CH][128];
    __shared__ __align__(16) u16 Xb[3][CH][64];
    __shared__ u16 idx16[CH * TT];                 // 2 KB
    __shared__ u32 mbits[TT];                      // 2 KB

    const int tid  = threadIdx.x;
    const int lane = tid & 63;
    const int wv   = tid >> 6;        // wave 0..7
    const int l15  = lane & 15;       // acc col
    const int c4   = lane >> 4;       // 0..3 (acc row group / B k-group)
    const int d    = blockIdx.x & 1;  // 0 fwd, 1 bwd
    const int g    = blockIdx.x >> 1; // 0..127
    const int b0   = g * CH;
    const int rev  = d;

    const int chain = l15 & 1;
    const int q     = (l15 >> 1) & 3; // acc row within c4 group
    const int role  = l15 >> 3;       // 0 = A (state-owner), 1 = B (helper)

    const float* Wih = d ? Wih_b : Wih_f;
    const float* Whh = d ? Whh_b : Whh_f;
    const float* bih = d ? bih_b : bih_f;
    const float* bhh = d ? bhh_b : bhh_f;

    // ---- init: idx (u16), mask bits, zero Hc + Xb (pads stay 0 forever)
    for (int i = tid; i < CH * TT; i += 512) {
        const int m = i >> 9, t = i & 511;
        idx16[i] = (u16)idx[(b0 + m) * TT + t];
    }
    if (tid < TT) {
        u32 mb = 0;
        for (int m = 0; m < CH; ++m)
            mb |= (masks[(b0 + m) * TT + tid] != 0.f ? 1u : 0u) << m;
        mbits[tid] = mb;
    }
    if (tid < 256) ((u32*)Hc)[tid] = 0u;        // 2*2*128 u16
    if (tid < 192) ((u32*)Xb)[tid] = 0u;        // 3*2*64 u16

    // ---- W fragments (A-operand) in VGPRs: w[kt][gt], gt = i/f/g/o.
    // Lane provides A[row = gate][k]: gate n = (wv + gt*8)*16 + l15,
    // k = kt*32 + c4*8 + j, j = 0..7.  (identical to R9-R17, proven)
    f16x8 w[6][4];
    f32x4 bias4[4];
#pragma unroll
    for (int gt = 0; gt < 4; ++gt) {
        const int n = (wv + gt * 8) * 16 + l15;
        {   // bias for acc rows: gates (wv+gt*8)*16 + c4*4 + q', q'=0..3
            const int nb_ = (wv + gt * 8) * 16 + c4 * 4;
            const float4 bi = *(const float4*)(bih + nb_);
            const float4 bh = *(const float4*)(bhh + nb_);
            bias4[gt][0] = bi.x + bh.x; bias4[gt][1] = bi.y + bh.y;
            bias4[gt][2] = bi.z + bh.z; bias4[gt][3] = bi.w + bh.w;
        }
        // kt = 0: k = c4*8 + j (< 32 < 50) -> Wih (float2 loads: 8B aligned)
#pragma unroll
        for (int jj = 0; jj < 4; ++jj) {
            const float2 e = *(const float2*)(Wih + n * 50 + c4 * 8 + jj * 2);
            w[0][gt][2 * jj]     = (f16)e.x;
            w[0][gt][2 * jj + 1] = (f16)e.y;
        }
        // kt = 1: k = 32 + c4*8 + j, real iff k < 50
#pragma unroll
        for (int j = 0; j < 8; ++j) {
            const int k = 32 + c4 * 8 + j;
            float v = 0.f;
            if (k < 50) v = Wih[n * 50 + k];
            w[1][gt][j] = (f16)v;
        }
        // kt = 2..5: k >= 64 -> Whh[n][k-64] (16B aligned float4 x2)
#pragma unroll
        for (int kt = 2; kt < 6; ++kt) {
            const int kh = (kt - 2) * 32 + c4 * 8;
            const float4 e0 = *(const float4*)(Whh + n * 128 + kh);
            const float4 e1 = *(const float4*)(Whh + n * 128 + kh + 4);
            w[kt][gt][0] = (f16)e0.x; w[kt][gt][1] = (f16)e0.y;
            w[kt][gt][2] = (f16)e0.z; w[kt][gt][3] = (f16)e0.w;
            w[kt][gt][4] = (f16)e1.x; w[kt][gt][5] = (f16)e1.y;
            w[kt][gt][6] = (f16)e1.z; w[kt][gt][7] = (f16)e1.w;
        }
    }

    __syncthreads();   // idx16/mbits/Hc/Xb zero visible before x store

    // ---- x staging lanes: wave 7, 50 lanes (2 chains x 25 half-pairs)
    const int  tid7 = tid - 448;
    const bool xthr = (tid7 >= 0) && (tid7 < 50);
    const int  xch  = xthr ? (tid7 / 25) : 0;
    const int  xps  = xthr ? (tid7 % 25) : 0;

    // ---- prologue: stage x(t(0)) -> Xb[0], x(t(1)) -> Xb[1]
    if (xthr) {
#pragma unroll
        for (int p = 0; p < 2; ++p) {
            const int tp  = rev ? (TT - 1 - p) : p;
            const int row = idx16[xch * TT + tp];
            const float2 e = *(const float2*)(emb + row * 50 + xps * 2);
            *(u32*)((unsigned char*)&Xb[p][0][0] + xch * 128 + xps * 4) =
                packh2(e.x, e.y);
        }
    }
    __syncthreads();

    // ---- initial xacc for step 0 from Xb[0]
    f32x4 xi = bias4[0], xf = bias4[1], xg = bias4[2], xo = bias4[3];
    {
        const unsigned char* xb =
            (const unsigned char*)&Xb[0][0][0] + chain * 128;
        const f16x8 b0 = *(const f16x8*)(xb + c4 * 16);
        const f16x8 b1 = *(const f16x8*)(xb + 64 + c4 * 16);
        xi = __builtin_amdgcn_mfma_f32_16x16x32_f16(w[0][0], b0, xi, 0, 0, 0);
        xf = __builtin_amdgcn_mfma_f32_16x16x32_f16(w[0][1], b0, xf, 0, 0, 0);
        xg = __builtin_amdgcn_mfma_f32_16x16x32_f16(w[0][2], b0, xg, 0, 0, 0);
        xo = __builtin_amdgcn_mfma_f32_16x16x32_f16(w[0][3], b0, xo, 0, 0, 0);
        xi = __builtin_amdgcn_mfma_f32_16x16x32_f16(w[1][0], b1, xi, 0, 0, 0);
        xf = __builtin_amdgcn_mfma_f32_16x16x32_f16(w[1][1], b1, xf, 0, 0, 0);
        xg = __builtin_amdgcn_mfma_f32_16x16x32_f16(w[1][2], b1, xg, 0, 0, 0);
        xo = __builtin_amdgcn_mfma_f32_16x16x32_f16(w[1][3], b1, xo, 0, 0, 0);
    }

    float cst = 0.f, rm = -3e38f;

    const int hd = wv * 16 + c4 * 4 + q;   // this lane's dim
    // writeback: lanes l15 in {0,1,4,5} (role 0, even q) write the dim-pair
    const bool wbthr = (l15 == 0) | (l15 == 1) | (l15 == 4) | (l15 == 5);

    int p1 = 1, p2 = 2, p0 = 0;  // (s+1)%3, (s+2)%3, s%3

    for (int s = 0; s < TT; ++s) {
        const int cur = s & 1;
        const int t   = rev ? (TT - 1 - s) : s;

        // prefetch x(t(s+2)) from global (wave 7; hidden under MFMA)
        float2 e;
        const bool pf = xthr && (s + 2 < TT);
        if (pf) {
            const int t2  = rev ? (TT - 3 - s) : (s + 2);
            const int row = idx16[xch * TT + t2];
            e = *(const float2*)(emb + row * 50 + xps * 2);
        }

        // ---- critical-path MFMA: acc starts from carried xacc; only the
        // 4 h-dependent K-tiles (kt 2..5) remain in the chain.
        const unsigned char* hb =
            (const unsigned char*)&Hc[cur][0][0] + chain * 256;
        f32x4 ai = xi, af = xf, ag = xg, ao = xo;
#pragma unroll
        for (int kt = 0; kt < 4; ++kt) {
            const f16x8 bf = *(const f16x8*)(hb + kt * 64 + c4 * 16);
            ai = __builtin_amdgcn_mfma_f32_16x16x32_f16(w[kt + 2][0], bf, ai, 0, 0, 0);
            af = __builtin_amdgcn_mfma_f32_16x16x32_f16(w[kt + 2][1], bf, af, 0, 0, 0);
            ag = __builtin_amdgcn_mfma_f32_16x16x32_f16(w[kt + 2][2], bf, ag, 0, 0, 0);
            ao = __builtin_amdgcn_mfma_f32_16x16x32_f16(w[kt + 2][3], bf, ao, 0, 0, 0);
        }

        // ---- off-path: compute next step's xacc from Xb[p1] (staged s-1;
        // independent of this step's chain -> scheduler fills pipe gaps).
        xi = bias4[0]; xf = bias4[1]; xg = bias4[2]; xo = bias4[3];
        {
            const unsigned char* xb =
                (const unsigned char*)&Xb[0][0][0] + p1 * 256 + chain * 128;
            const f16x8 b0 = *(const f16x8*)(xb + c4 * 16);
            const f16x8 b1 = *(const f16x8*)(xb + 64 + c4 * 16);
            xi = __builtin_amdgcn_mfma_f32_16x16x32_f16(w[0][0], b0, xi, 0, 0, 0);
            xf = __builtin_amdgcn_mfma_f32_16x16x32_f16(w[0][1], b0, xf, 0, 0, 0);
            xg = __builtin_amdgcn_mfma_f32_16x16x32_f16(w[0][2], b0, xg, 0, 0, 0);
            xo = __builtin_amdgcn_mfma_f32_16x16x32_f16(w[0][3], b0, xo, 0, 0, 0);
            xi = __builtin_amdgcn_mfma_f32_16x16x32_f16(w[1][0], b1, xi, 0, 0, 0);
            xf = __builtin_amdgcn_mfma_f32_16x16x32_f16(w[1][1], b1, xf, 0, 0, 0);
            xg = __builtin_amdgcn_mfma_f32_16x16x32_f16(w[1][2], b1, xg, 0, 0, 0);
            xo = __builtin_amdgcn_mfma_f32_16x16x32_f16(w[1][3], b1, xo, 0, 0, 0);
        }

        // ---- q-row select
        const float iv = sel4(ai, q);
        const float fv = sel4(af, q);
        const float gv = sel4(ag, q);
        const float ov = sel4(ao, q);

        // ---- SIMT role-split activation, DPP transport (R13-R17 proven):
        // role A: su=sig(f), sv=sig(i); role B: su=sig(2g), sv=sig(o)
        const bool rB = (role != 0);
        const float u_in = rB ? (gv + gv) : fv;
        const float v_in = rB ? ov : iv;
        const float su = sigf(u_in);
        const float sv = sigf(v_in);
        const float tg_send = 2.f * su - 1.f;     // B: tanh(g); A: junk
        const float tgx = xor8(tg_send);          // A receives tanh(g)
        const float svx = xor8(sv);               // A receives sig(o)
        const float cc = su * cst + sv * tgx;     // A: valid c; B: junk chain
        cst = cc;
        const float ccx = xor8(cc);               // B receives A's cc
        const float cc_use = rB ? ccx : cc;
        const float th = 2.f * sigf(cc_use + cc_use) - 1.f;   // tanh(c)
        const float so_use = rB ? sv : svx;       // sig(o) in both roles
        const float hh = so_use * th;             // VALID in all lanes

        const float pen = ((mbits[t] >> chain) & 1u) ? 0.f : 1e8f;
        rm = fmaxf(rm, hh - pen);

        // ---- writeback: h single copy (dim-pair via DPP xor2) + x stage
        const float hx2 = xor2(hh);               // neighbor dim's h (q^1)
        if (wbthr) {
            *(u32*)((unsigned char*)&Hc[cur ^ 1][0][0] + chain * 256 + hd * 2) =
                packh2(hh, hx2);
        }
        if (pf) {
            *(u32*)((unsigned char*)&Xb[0][0][0] + p2 * 256 + xch * 128 + xps * 4) =
                packh2(e.x, e.y);
        }
        __syncthreads();

        // rotate x-slot indices: {p0,p1,p2} <- {p1,p2,p0}
        const int tmp = p0; p0 = p1; p1 = p2; p2 = tmp;
    }

    // ---- output: lanes l15 < 8 give unique (chain, q) -> one per dim
    if (l15 < 8) {
        out[(b0 + chain) * 256 + d * 128 + hd] = rm;
    }
}

extern "C" void kernel_launch(void* const* d_in, const int* in_sizes, int n_in,
                              void* d_out, int out_size, void* d_ws, size_t ws_size,
                              hipStream_t stream) {
    const int*   idx   = (const int*)d_in[0];
    const float* masks = (const float*)d_in[1];
    const float* emb   = (const float*)d_in[2];
    const float* Wih_f = (const float*)d_in[3];
    const float* Whh_f = (const float*)d_in[4];
    const float* bih_f = (const float*)d_in[5];
    const float* bhh_f = (const float*)d_in[6];
    const float* Wih_b = (const float*)d_in[7];
    const float* Whh_b = (const float*)d_in[8];
    const float* bih_b = (const float*)d_in[9];
    const float* bhh_b = (const float*)d_in[10];
    float* out = (float*)d_out;

    bilstm_xla_kernel<<<dim3(256), dim3(512), 0, stream>>>(
        idx, masks, emb,
        Wih_f, Whh_f, bih_f, bhh_f,
        Wih_b, Whh_b, bih_b, bhh_b,
        out);
}